// Round 8
// baseline (331.762 us; speedup 1.0000x reference)
//
#include <hip/hip_runtime.h>
#include <math.h>

#define N_PTS 4096
#define KNN   16
#define DFEAT 64
#define DOUT  128
#define CTOT  192   // DOUT + DFEAT

#define QPB   32    // queries per block = 16 waves x 2 halves
#define LPQ   32    // lanes per query (half-wave)

// Packed ranking key: hi32 = float bits of d2 (>= 0 so unsigned order ==
// float order), lo32 = j. Unsigned 64-bit compare == lexicographic (d2, j),
// exactly lax.top_k's stable tie-break. d2 formula identical to reference:
// (sq_i + sq_j) - 2*dot, clamped at 0.
__device__ __forceinline__ unsigned long long key_of(float4 ci, float4 cj, int j) {
    float dot = ci.x * cj.x + ci.y * cj.y + ci.z * cj.z;
    float d2  = fmaxf((ci.w + cj.w) - 2.0f * dot, 0.0f);
    return ((unsigned long long)__float_as_uint(d2) << 32) | (unsigned)j;
}

// Branchless sorted insert into ascending 4-list k1<=k2<=k3<=k4.
#define INSERT4(kk)                                   \
    do {                                              \
        bool c1 = (kk) < k1, c2 = (kk) < k2;          \
        bool c3 = (kk) < k3, c4 = (kk) < k4;          \
        k4 = c3 ? k3 : (c4 ? (kk) : k4);              \
        k3 = c2 ? k2 : (c3 ? (kk) : k3);              \
        k2 = c1 ? k1 : (c2 ? (kk) : k2);              \
        k1 = c1 ? (kk) : k1;                          \
    } while (0)

// ---------------- Kernel 1: exact KNN — UNCHANGED from round 6 ----------
__global__ __launch_bounds__(1024) void knn_kernel(
    const float* __restrict__ coords,
    int* __restrict__ idx_ws,
    float* __restrict__ dist_ws)
{
    __shared__ float4 cs[N_PTS];
    const int tid = threadIdx.x;
    const int q0  = blockIdx.x * QPB;
    const int b   = q0 >> 12;            // all QPB queries share a batch

    const float* cb = coords + (size_t)b * N_PTS * 3;
    for (int j = tid; j < N_PTS; j += 1024) {
        float x = cb[j * 3 + 0], y = cb[j * 3 + 1], z = cb[j * 3 + 2];
        cs[j] = make_float4(x, y, z, x * x + y * y + z * z);
    }
    __syncthreads();

    const int wave = tid >> 6;
    const int lane = tid & 63;
    const int half = lane >> 5;          // which of the wave's 2 queries
    const int hl   = lane & 31;          // lane index within the query group
    const int q    = q0 + wave * 2 + half;
    const int n    = q & (N_PTS - 1);

    const float4 ci = cs[n];

    const unsigned long long KSENT = 0xFFFFFFFFFFFFFFFFull;
    unsigned long long k1 = KSENT, k2 = KSENT, k3 = KSENT, k4 = KSENT;

    for (int t = 0; t < 128; ++t) {
        int j = (t << 5) + hl;
        unsigned long long kk = key_of(ci, cs[j], j);
        INSERT4(kk);
    }

    unsigned long long tak0 = 0ull, tak1 = 0ull;  // extracted slots (t<64 / t>=64)
    unsigned long long outKey = 0ull;

    for (int k = 0; k < KNN; ++k) {
        unsigned long long rk = k1;
        #pragma unroll
        for (int s = 1; s < LPQ; s <<= 1) {
            unsigned long long o = __shfl_xor(rk, s);
            if (o < rk) rk = o;
        }
        if (hl == k) outKey = rk;

        if (k1 == rk) {
            int t = (int)(rk & 0xFFFFFFFFull) >> 5;
            if (t < 64) tak0 |= 1ull << t;
            else        tak1 |= 1ull << (t - 64);
            k1 = k2; k2 = k3; k3 = k4; k4 = KSENT;
        }

        if (k1 == KSENT && k < KNN - 1) {
            k2 = KSENT; k3 = KSENT; k4 = KSENT;
            for (int t = 0; t < 64; ++t) {
                if ((tak0 >> t) & 1ull) continue;
                int j = (t << 5) + hl;
                unsigned long long kk = key_of(ci, cs[j], j);
                INSERT4(kk);
            }
            for (int t = 64; t < 128; ++t) {
                if ((tak1 >> (t - 64)) & 1ull) continue;
                int j = (t << 5) + hl;
                unsigned long long kk = key_of(ci, cs[j], j);
                INSERT4(kk);
            }
        }
    }

    if (hl < KNN) {
        float d2 = __uint_as_float((unsigned)(outKey >> 32));
        idx_ws[q * KNN + hl]  = (int)(outKey & 0xFFFFFFFFull);
        dist_ws[q * KNN + hl] = sqrtf(fmaxf(d2, 1e-12f));
    }
}

// ---------------- Kernel 2: encode + MLP + concat, 4 k per thread --------
// One thread per (b, n, k-quad): handles k = 4*qd .. 4*qd+3. Every store is
// a float4 (16 B/lane, consecutive lanes contiguous -> perfect coalescing);
// W-row LDS reads amortized over 4 outputs; idx/dist loaded as int4/float4.
__global__ __launch_bounds__(256) void out_kernel(
    const float* __restrict__ coords, const float* __restrict__ features,
    const float* __restrict__ W, const float* __restrict__ bias,
    const int* __restrict__ idx_ws, const float* __restrict__ dist_ws,
    float* __restrict__ out)
{
    __shared__ float Ws[DOUT * 12];   // rows padded 10 -> 12 for b128 reads
    __shared__ float bs[DOUT];
    const int tid = threadIdx.x;
    for (int i = tid; i < DOUT * 12; i += 256) {
        int o = i / 12, t = i - o * 12;
        Ws[i] = (t < 10) ? W[o * 10 + t] : 0.0f;
    }
    if (tid < DOUT) bs[tid] = bias[tid];
    __syncthreads();

    const int g  = blockIdx.x * 256 + tid;    // flat (b, n, quad)
    const int qd = g & 3;                     // k-quad: k = 4*qd + 0..3
    const int n  = (g >> 2) & (N_PTS - 1);
    const int b  = g >> 14;

    const int gq = ((b << 12) + n) * KNN + (qd << 2);   // flat (b,n,k) base
    const int4   nb4 = *reinterpret_cast<const int4*>(&idx_ws[gq]);
    const float4 dt4 = *reinterpret_cast<const float4*>(&dist_ws[gq]);

    const float* cb = coords + (size_t)b * N_PTS * 3;
    const float pix = cb[n * 3 + 0], piy = cb[n * 3 + 1], piz = cb[n * 3 + 2];

    // neighbor coords (4 gathers; L1/L2-resident)
    float pjx0 = cb[nb4.x * 3 + 0], pjy0 = cb[nb4.x * 3 + 1], pjz0 = cb[nb4.x * 3 + 2];
    float pjx1 = cb[nb4.y * 3 + 0], pjy1 = cb[nb4.y * 3 + 1], pjz1 = cb[nb4.y * 3 + 2];
    float pjx2 = cb[nb4.z * 3 + 0], pjy2 = cb[nb4.z * 3 + 1], pjz2 = cb[nb4.z * 3 + 2];
    float pjx3 = cb[nb4.w * 3 + 0], pjy3 = cb[nb4.w * 3 + 1], pjz3 = cb[nb4.w * 3 + 2];

    // out element base: [b][c][n][k] with k-quad contiguous (16 B)
    float* outb = out + (size_t)b * CTOT * N_PTS * KNN
                      + (size_t)n * KNN + (qd << 2);

    #pragma unroll 2
    for (int o = 0; o < DOUT; ++o) {
        const float4 w0 = *reinterpret_cast<const float4*>(&Ws[o * 12 + 0]);
        const float4 w1 = *reinterpret_cast<const float4*>(&Ws[o * 12 + 4]);
        const float2 w2 = *reinterpret_cast<const float2*>(&Ws[o * 12 + 8]);
        // shared p_i part + bias
        const float base = bs[o] + pix * w0.x + piy * w0.y + piz * w0.z;
        float4 r;
        r.x = base + pjx0 * w0.w + pjy0 * w1.x + pjz0 * w1.y
                   + (pix - pjx0) * w1.z + (piy - pjy0) * w1.w
                   + (piz - pjz0) * w2.x + dt4.x * w2.y;
        r.y = base + pjx1 * w0.w + pjy1 * w1.x + pjz1 * w1.y
                   + (pix - pjx1) * w1.z + (piy - pjy1) * w1.w
                   + (piz - pjz1) * w2.x + dt4.y * w2.y;
        r.z = base + pjx2 * w0.w + pjy2 * w1.x + pjz2 * w1.y
                   + (pix - pjx2) * w1.z + (piy - pjy2) * w1.w
                   + (piz - pjz2) * w2.x + dt4.z * w2.y;
        r.w = base + pjx3 * w0.w + pjy3 * w1.x + pjz3 * w1.y
                   + (pix - pjx3) * w1.z + (piy - pjy3) * w1.w
                   + (piz - pjz3) * w2.x + dt4.w * w2.y;
        *reinterpret_cast<float4*>(&outb[(size_t)o * (N_PTS * KNN)]) = r;
    }

    const float* fb = features + (size_t)b * DFEAT * N_PTS + n;
    float* outf = outb + (size_t)DOUT * (N_PTS * KNN);
    #pragma unroll 4
    for (int f = 0; f < DFEAT; ++f) {
        const float v = fb[(size_t)f * N_PTS];
        *reinterpret_cast<float4*>(&outf[(size_t)f * (N_PTS * KNN)]) =
            make_float4(v, v, v, v);
    }
}

extern "C" void kernel_launch(void* const* d_in, const int* in_sizes, int n_in,
                              void* d_out, int out_size, void* d_ws, size_t ws_size,
                              hipStream_t stream) {
    (void)n_in; (void)out_size; (void)ws_size;
    const float* coords   = (const float*)d_in[0];
    const float* features = (const float*)d_in[1];
    const float* W        = (const float*)d_in[2];
    const float* bias     = (const float*)d_in[3];
    float* out = (float*)d_out;

    const int B  = in_sizes[0] / (N_PTS * 3);   // 4
    const int nq = B * N_PTS;                   // 16384 queries

    int*   idx_ws  = (int*)d_ws;
    float* dist_ws = (float*)((char*)d_ws + (size_t)nq * KNN * sizeof(int));

    knn_kernel<<<nq / QPB, 1024, 0, stream>>>(coords, idx_ws, dist_ws);
    out_kernel<<<(nq * KNN / 4) / 256, 256, 0, stream>>>(
        coords, features, W, bias, idx_ws, dist_ws, out);
}